// Round 1
// baseline (4261.602 us; speedup 1.0000x reference)
//
#include <hip/hip_runtime.h>
#include <math.h>

__device__ __forceinline__ float silu(float x) { return x / (1.0f + __expf(-x)); }

// ---------------- Kernel 1: per-node precompute ----------------
// y[n][0:32]   = x0 @ lin1_w0 / sqrt(32)
// y[n][32+u*3+i] = (x1 @_u lin1_w1)[w][i] / sqrt(32)
// sc[n][0:64]  = einsum(x0, na, sc_w0) / sqrt(128)
// sc[n][64+w*3+i] = einsum(x1, na, sc_w1) / sqrt(128)
__global__ __launch_bounds__(320) void node_pre_kernel(
    const float* __restrict__ nf, const float* __restrict__ na,
    const float* __restrict__ w0, const float* __restrict__ w1,
    const float* __restrict__ scw0, const float* __restrict__ scw1,
    float* __restrict__ y, float* __restrict__ sc)
{
  __shared__ float snf[128];
  __shared__ float sna[4];
  const int n = blockIdx.x;
  const int t = threadIdx.x;
  if (t < 128) snf[t] = nf[n * 128 + t];
  if (t >= 128 && t < 132) sna[t - 128] = na[n * 4 + (t - 128)];
  __syncthreads();
  const float inv_sqrt32 = 0.17677669529663687f;
  const float sc_norm    = 0.08838834764831843f;  // 1/sqrt(32*4)
  if (t < 32) {
    const int w = t;
    float acc = 0.f;
    for (int u = 0; u < 32; ++u) acc += snf[u] * w0[u * 32 + w];
    y[n * 128 + w] = acc * inv_sqrt32;
  } else if (t < 128) {
    const int q = t - 32, w = q / 3, i = q - w * 3;
    float acc = 0.f;
    for (int u = 0; u < 32; ++u) acc += snf[32 + u * 3 + i] * w1[u * 32 + w];
    y[n * 128 + 32 + w * 3 + i] = acc * inv_sqrt32;
  } else if (t < 192) {
    const int w = t - 128;
    float acc = 0.f;
    for (int k = 0; k < 128; ++k) acc += snf[k >> 2] * sna[k & 3] * scw0[k * 64 + w];
    sc[n * 160 + w] = acc * sc_norm;
  } else if (t < 288) {
    const int q = t - 192, w = q / 3, i = q - w * 3;
    float acc = 0.f;
    for (int k = 0; k < 128; ++k) acc += snf[32 + (k >> 2) * 3 + i] * sna[k & 3] * scw1[k * 32 + w];
    sc[n * 160 + 64 + w * 3 + i] = acc * sc_norm;
  }
}

// ---------------- Kernel 2: per-edge MLP + tensor product + scatter ----------------
__global__ __launch_bounds__(256) void edge_kernel(
    const float* __restrict__ eattr, const float* __restrict__ eemb,
    const float* __restrict__ fw1, const float* __restrict__ fw2,
    const float* __restrict__ fw3, const int* __restrict__ eidx,
    const float* __restrict__ y, float* __restrict__ m, int E)
{
  __shared__ __align__(16) float w1T[512];    // [j<64][k<8]
  __shared__ __align__(16) float w2T[4096];   // [j<64][k<64]
  __shared__ __align__(16) float w3T[8192];   // [col<128][k<64]
  const int t = threadIdx.x;
  for (int x = t; x < 512; x += 256)  w1T[x] = fw1[(x & 7) * 64 + (x >> 3)];
  for (int x = t; x < 4096; x += 256) w2T[x] = fw2[(x & 63) * 64 + (x >> 6)];
  for (int x = t; x < 8192; x += 256) { const int k = x >> 7, cu = x & 127; w3T[cu * 64 + k] = fw3[x]; }
  __syncthreads();

  const int e = blockIdx.x * 256 + t;
  if (e >= E) return;
  const int src = eidx[e];
  const int dst = eidx[E + e];

  const float4 emb0 = *(const float4*)(eemb + (size_t)e * 8);
  const float4 emb1 = *(const float4*)(eemb + (size_t)e * 8 + 4);
  const float emb[8] = {emb0.x, emb0.y, emb0.z, emb0.w, emb1.x, emb1.y, emb1.z, emb1.w};

  const float inv_sqrt8 = 0.35355339059327373f;
  float h1[64];
#pragma unroll
  for (int j = 0; j < 64; ++j) {
    const float4* p = (const float4*)(w1T + j * 8);
    const float4 wa = p[0], wb = p[1];
    float acc = emb[0] * wa.x + emb[1] * wa.y + emb[2] * wa.z + emb[3] * wa.w
              + emb[4] * wb.x + emb[5] * wb.y + emb[6] * wb.z + emb[7] * wb.w;
    h1[j] = silu(acc * inv_sqrt8);
  }
  float h2[64];
#pragma unroll
  for (int j = 0; j < 64; ++j) {
    const float4* p = (const float4*)(w2T + j * 64);
    float acc = 0.f;
#pragma unroll
    for (int kk = 0; kk < 16; ++kk) {
      const float4 w = p[kk];
      acc += h1[kk * 4 + 0] * w.x + h1[kk * 4 + 1] * w.y
           + h1[kk * 4 + 2] * w.z + h1[kk * 4 + 3] * w.w;
    }
    h2[j] = silu(acc * 0.125f);
  }

  const float4 ea = *(const float4*)(eattr + (size_t)e * 4);
  const float e0 = ea.x, e1x = ea.y, e1y = ea.z, e1z = ea.w;
  const float inv_sqrt3 = 0.5773502691896258f;
  const float* yrow = y + (size_t)src * 128;
  float* mrow = m + (size_t)dst * 256;

  for (int u4 = 0; u4 < 8; ++u4) {
    const int u0 = u4 * 4;
    const float4 G0 = *(const float4*)(yrow + u0);
    const float4 GA = *(const float4*)(yrow + 32 + u0 * 3);
    const float4 GB = *(const float4*)(yrow + 32 + u0 * 3 + 4);
    const float4 GC = *(const float4*)(yrow + 32 + u0 * 3 + 8);
    const float g0[4]    = {G0.x, G0.y, G0.z, G0.w};
    const float g1[4][3] = {{GA.x, GA.y, GA.z}, {GA.w, GB.x, GB.y},
                            {GB.z, GB.w, GC.x}, {GC.y, GC.z, GC.w}};
    float a[4][4];
#pragma unroll
    for (int q = 0; q < 4; ++q)
#pragma unroll
      for (int c = 0; c < 4; ++c) a[q][c] = 0.f;
#pragma unroll
    for (int kk = 0; kk < 16; ++kk) {
#pragma unroll
      for (int q = 0; q < 4; ++q) {
#pragma unroll
        for (int c = 0; c < 4; ++c) {
          const float4 w = *(const float4*)(w3T + (c * 32 + u0 + q) * 64 + kk * 4);
          a[q][c] += h2[kk * 4 + 0] * w.x + h2[kk * 4 + 1] * w.y
                   + h2[kk * 4 + 2] * w.z + h2[kk * 4 + 3] * w.w;
        }
      }
    }
#pragma unroll
    for (int q = 0; q < 4; ++q) {
      const int u = u0 + q;
      const float w00 = a[q][0] * 0.125f, w01 = a[q][1] * 0.125f;
      const float w10 = a[q][2] * 0.125f, w11 = a[q][3] * 0.125f;
      const float os0 = w00 * g0[q] * e0;
      const float dotg = g1[q][0] * e1x + g1[q][1] * e1y + g1[q][2] * e1z;
      const float os1 = w11 * dotg * inv_sqrt3;
      const float t01 = w01 * g0[q];
      const float wg  = w10 * e0;
      atomicAdd(mrow + u, os0);
      atomicAdd(mrow + 32 + u, os1);
      atomicAdd(mrow + 64 + u * 3 + 0, t01 * e1x);
      atomicAdd(mrow + 64 + u * 3 + 1, t01 * e1y);
      atomicAdd(mrow + 64 + u * 3 + 2, t01 * e1z);
      atomicAdd(mrow + 160 + u * 3 + 0, wg * g1[q][0]);
      atomicAdd(mrow + 160 + u * 3 + 1, wg * g1[q][1]);
      atomicAdd(mrow + 160 + u * 3 + 2, wg * g1[q][2]);
    }
  }
}

// ---------------- Kernel 3: per-node output ----------------
__global__ __launch_bounds__(192) void node_out_kernel(
    const float* __restrict__ nf, const float* __restrict__ mg,
    const float* __restrict__ sc, const float* __restrict__ w0,
    const float* __restrict__ w1, const int* __restrict__ avgp,
    float* __restrict__ out)
{
  __shared__ float sm[256];
  __shared__ float so0[64];
  __shared__ float so1[96];
  const int n = blockIdx.x, t = threadIdx.x;
  const float inv_avg = rsqrtf((float)(*avgp));
  for (int k = t; k < 256; k += 192) sm[k] = mg[n * 256 + k] * inv_avg;
  __syncthreads();
  if (t < 64) {
    float acc = 0.f;
    for (int u = 0; u < 64; ++u) acc += sm[u] * w0[u * 64 + t];
    so0[t] = acc * 0.125f + sc[n * 160 + t];
  } else if (t < 160) {
    const int q = t - 64, w = q / 3, i = q - w * 3;
    float acc = 0.f;
    for (int u = 0; u < 64; ++u) acc += sm[64 + u * 3 + i] * w1[u * 32 + w];
    so1[w * 3 + i] = acc * 0.125f + sc[n * 160 + 64 + w * 3 + i];
  }
  __syncthreads();
  if (t < 32) {
    out[n * 128 + t] = nf[n * 128 + t] + silu(so0[t]);
  } else if (t < 128) {
    const int q = t - 32, w = q / 3, i = q - w * 3;
    out[n * 128 + t] = nf[n * 128 + t] + silu(so0[32 + w]) * so1[w * 3 + i];
  }
}

extern "C" void kernel_launch(void* const* d_in, const int* in_sizes, int n_in,
                              void* d_out, int out_size, void* d_ws, size_t ws_size,
                              hipStream_t stream)
{
  const float* nf    = (const float*)d_in[0];
  const float* na    = (const float*)d_in[1];
  const float* eattr = (const float*)d_in[2];
  const float* eemb  = (const float*)d_in[3];
  const float* l1w0  = (const float*)d_in[4];
  const float* l1w1  = (const float*)d_in[5];
  const float* fw1   = (const float*)d_in[6];
  const float* fw2   = (const float*)d_in[7];
  const float* fw3   = (const float*)d_in[8];
  const float* l2w0  = (const float*)d_in[9];
  const float* l2w1  = (const float*)d_in[10];
  const float* scw0  = (const float*)d_in[11];
  const float* scw1  = (const float*)d_in[12];
  const int*   eidx  = (const int*)d_in[13];
  const int*   avgp  = (const int*)d_in[14];

  const int N = in_sizes[0] / 128;
  const int E = in_sizes[2] / 4;

  float* m  = (float*)d_ws;                  // N*256 floats
  float* y  = m + (size_t)N * 256;           // N*128 floats
  float* sc = y + (size_t)N * 128;           // N*160 floats

  hipMemsetAsync(m, 0, (size_t)N * 256 * sizeof(float), stream);
  node_pre_kernel<<<N, 320, 0, stream>>>(nf, na, l1w0, l1w1, scw0, scw1, y, sc);
  edge_kernel<<<(E + 255) / 256, 256, 0, stream>>>(eattr, eemb, fw1, fw2, fw3, eidx, y, m, E);
  node_out_kernel<<<N, 192, 0, stream>>>(nf, m, sc, l2w0, l2w1, avgp, (float*)d_out);
}

// Round 2
// 814.477 us; speedup vs baseline: 5.2323x; 5.2323x over previous
//
#include <hip/hip_runtime.h>
#include <math.h>

__device__ __forceinline__ float silu(float x) { return x / (1.0f + __expf(-x)); }

// ---------------- Kernel 1: per-node precompute (unchanged) ----------------
__global__ __launch_bounds__(320) void node_pre_kernel(
    const float* __restrict__ nf, const float* __restrict__ na,
    const float* __restrict__ w0, const float* __restrict__ w1,
    const float* __restrict__ scw0, const float* __restrict__ scw1,
    float* __restrict__ y, float* __restrict__ sc)
{
  __shared__ float snf[128];
  __shared__ float sna[4];
  const int n = blockIdx.x;
  const int t = threadIdx.x;
  if (t < 128) snf[t] = nf[n * 128 + t];
  if (t >= 128 && t < 132) sna[t - 128] = na[n * 4 + (t - 128)];
  __syncthreads();
  const float inv_sqrt32 = 0.17677669529663687f;
  const float sc_norm    = 0.08838834764831843f;  // 1/sqrt(32*4)
  if (t < 32) {
    const int w = t;
    float acc = 0.f;
    for (int u = 0; u < 32; ++u) acc += snf[u] * w0[u * 32 + w];
    y[n * 128 + w] = acc * inv_sqrt32;
  } else if (t < 128) {
    const int q = t - 32, w = q / 3, i = q - w * 3;
    float acc = 0.f;
    for (int u = 0; u < 32; ++u) acc += snf[32 + u * 3 + i] * w1[u * 32 + w];
    y[n * 128 + 32 + w * 3 + i] = acc * inv_sqrt32;
  } else if (t < 192) {
    const int w = t - 128;
    float acc = 0.f;
    for (int k = 0; k < 128; ++k) acc += snf[k >> 2] * sna[k & 3] * scw0[k * 64 + w];
    sc[n * 160 + w] = acc * sc_norm;
  } else if (t < 288) {
    const int q = t - 192, w = q / 3, i = q - w * 3;
    float acc = 0.f;
    for (int k = 0; k < 128; ++k) acc += snf[32 + (k >> 2) * 3 + i] * sna[k & 3] * scw1[k * 32 + w];
    sc[n * 160 + 64 + w * 3 + i] = acc * sc_norm;
  }
}

// ---------------- Kernel 2: per-edge MLP -> w[128] scratch ----------------
// Weight accesses are wave-uniform -> compiler emits scalar loads; no LDS.
__global__ __launch_bounds__(256) void edge_mlp_kernel(
    const float* __restrict__ eemb, const float* __restrict__ fw1,
    const float* __restrict__ fw2, const float* __restrict__ fw3,
    float* __restrict__ wbuf, int E)
{
  const int e = blockIdx.x * 256 + threadIdx.x;
  if (e >= E) return;
  const float4 emb0 = *(const float4*)(eemb + (size_t)e * 8);
  const float4 emb1 = *(const float4*)(eemb + (size_t)e * 8 + 4);
  const float emb[8] = {emb0.x, emb0.y, emb0.z, emb0.w, emb1.x, emb1.y, emb1.z, emb1.w};
  const float inv_sqrt8 = 0.35355339059327373f;

  // h2[j] accumulated over k; h1[k] computed on the fly (never stored as array)
  float acc[64];
#pragma unroll
  for (int j = 0; j < 64; ++j) acc[j] = 0.f;
  for (int k = 0; k < 64; ++k) {
    float a = 0.f;
#pragma unroll
    for (int r = 0; r < 8; ++r) a += emb[r] * fw1[r * 64 + k];
    const float h1k = silu(a * inv_sqrt8);
    const float* row = fw2 + k * 64;
#pragma unroll
    for (int j = 0; j < 64; ++j) acc[j] += h1k * row[j];
  }
  float h2[64];
#pragma unroll
  for (int j = 0; j < 64; ++j) h2[j] = silu(acc[j] * 0.125f);

  float* wout = wbuf + (size_t)e * 128;
#pragma unroll
  for (int c0 = 0; c0 < 128; c0 += 32) {
    float aw[32];
#pragma unroll
    for (int c = 0; c < 32; ++c) aw[c] = 0.f;
#pragma unroll
    for (int k = 0; k < 64; ++k) {
      const float* row = fw3 + k * 128 + c0;
#pragma unroll
      for (int c = 0; c < 32; ++c) aw[c] += h2[k] * row[c];
    }
#pragma unroll
    for (int c = 0; c < 32; c += 4) {
      float4 v;
      v.x = aw[c] * 0.125f; v.y = aw[c + 1] * 0.125f;
      v.z = aw[c + 2] * 0.125f; v.w = aw[c + 3] * 0.125f;
      *(float4*)(wout + c0 + c) = v;
    }
  }
}

// ---------------- CSR build ----------------
__global__ __launch_bounds__(256) void hist_kernel(const int* __restrict__ eidx,
                                                   int* __restrict__ counts, int E)
{
  const int e = blockIdx.x * 256 + threadIdx.x;
  if (e < E) atomicAdd(&counts[eidx[E + e]], 1);
}

__global__ __launch_bounds__(1024) void scan_kernel(const int* __restrict__ counts,
                                                    int* __restrict__ offsets,
                                                    int* __restrict__ cursor, int N)
{
  __shared__ int part[1024];
  const int t = threadIdx.x;
  const int per = (N + 1023) / 1024;
  const int base = t * per;
  int s = 0;
  for (int k = 0; k < per; ++k) { int idx = base + k; if (idx < N) s += counts[idx]; }
  part[t] = s;
  __syncthreads();
  for (int off = 1; off < 1024; off <<= 1) {
    int v = part[t];
    if (t >= off) v += part[t - off];
    __syncthreads();
    part[t] = v;
    __syncthreads();
  }
  int run = (t == 0) ? 0 : part[t - 1];
  for (int k = 0; k < per; ++k) {
    int idx = base + k;
    if (idx < N) { offsets[idx] = run; cursor[idx] = run; run += counts[idx]; }
  }
  if (t == 1023) offsets[N] = run;
}

__global__ __launch_bounds__(256) void scatter_kernel(const int* __restrict__ eidx,
                                                      int* __restrict__ cursor,
                                                      int* __restrict__ elist, int E)
{
  const int e = blockIdx.x * 256 + threadIdx.x;
  if (e >= E) return;
  const int dst = eidx[E + e];
  const int slot = atomicAdd(&cursor[dst], 1);
  elist[slot] = e;
}

// ---------------- Kernel 3: gather + tensor product + lin2 + gate + residual --
__global__ __launch_bounds__(256) void gather_out_kernel(
    const float* __restrict__ nf, const float* __restrict__ wbuf,
    const float* __restrict__ y, const float* __restrict__ sc,
    const float* __restrict__ l2w0, const float* __restrict__ l2w1,
    const int* __restrict__ offsets, const int* __restrict__ elist,
    const int* __restrict__ eidx, const float* __restrict__ eattr,
    const int* __restrict__ avgp, float* __restrict__ out, int E)
{
  __shared__ float sm[256];
  __shared__ float so0[64];
  __shared__ float so1[96];
  const int n = blockIdx.x, t = threadIdx.x;

  // per-thread component mapping (branchless inner loop)
  int wi, yi0, yi1, yi2, selA;  // selA: 0=e0,1=e1x,2=e1y,3=e1z
  bool is1 = false;
  if (t < 32) {            // o_s0[u]
    wi = t; yi0 = yi1 = yi2 = t; selA = 0;
  } else if (t < 64) {     // o_s1[u]
    const int u = t - 32;
    wi = 96 + u; yi0 = 32 + 3 * u; yi1 = yi0 + 1; yi2 = yi0 + 2; selA = 1; is1 = true;
  } else if (t < 160) {    // o_v0[u][i]
    const int q = t - 64, u = q / 3, i = q - u * 3;
    wi = 32 + u; yi0 = yi1 = yi2 = u; selA = 1 + i;
  } else {                 // o_v1[u][i]
    const int q = t - 160, u = q / 3, i = q - u * 3;
    wi = 64 + u; yi0 = yi1 = yi2 = 32 + 3 * u + i; selA = 0;
  }

  const int beg = offsets[n], end = offsets[n + 1];
  float accv = 0.f;
  int eid = (beg < end) ? elist[beg] : 0;
  for (int j = beg; j < end; ++j) {
    const int eidn = (j + 1 < end) ? elist[j + 1] : 0;
    const int src = eidx[eid];
    const float4 ea = *(const float4*)(eattr + (size_t)eid * 4);
    const float* wr = wbuf + (size_t)eid * 128;
    const float* yr = y + (size_t)src * 128;
    const float A = (selA == 0) ? ea.x : (selA == 1) ? ea.y : (selA == 2) ? ea.z : ea.w;
    const float B = is1 ? ea.z : 0.f;
    const float C = is1 ? ea.w : 0.f;
    accv += wr[wi] * (A * yr[yi0] + B * yr[yi1] + C * yr[yi2]);
    eid = eidn;
  }
  const float inv_sqrt3 = 0.5773502691896258f;
  if (is1) accv *= inv_sqrt3;
  sm[t] = accv * rsqrtf((float)(*avgp));
  __syncthreads();

  if (t < 64) {
    float acc = 0.f;
    for (int u = 0; u < 64; ++u) acc += sm[u] * l2w0[u * 64 + t];
    so0[t] = acc * 0.125f + sc[n * 160 + t];
  } else if (t < 160) {
    const int q = t - 64, w = q / 3, i = q - w * 3;
    float acc = 0.f;
    for (int u = 0; u < 64; ++u) acc += sm[64 + u * 3 + i] * l2w1[u * 32 + w];
    so1[w * 3 + i] = acc * 0.125f + sc[n * 160 + 64 + w * 3 + i];
  }
  __syncthreads();
  if (t < 32) {
    out[n * 128 + t] = nf[n * 128 + t] + silu(so0[t]);
  } else if (t < 128) {
    const int q = t - 32, w = q / 3, i = q - w * 3;
    out[n * 128 + t] = nf[n * 128 + t] + silu(so0[32 + w]) * so1[w * 3 + i];
  }
}

// ---------------- Fallback (atomic path, used only if ws too small) --------
__global__ __launch_bounds__(256) void edge_kernel_atomic(
    const float* __restrict__ eattr, const float* __restrict__ eemb,
    const float* __restrict__ fw1, const float* __restrict__ fw2,
    const float* __restrict__ fw3, const int* __restrict__ eidx,
    const float* __restrict__ y, float* __restrict__ m, int E)
{
  __shared__ __align__(16) float w1T[512];
  __shared__ __align__(16) float w2T[4096];
  __shared__ __align__(16) float w3T[8192];
  const int t = threadIdx.x;
  for (int x = t; x < 512; x += 256)  w1T[x] = fw1[(x & 7) * 64 + (x >> 3)];
  for (int x = t; x < 4096; x += 256) w2T[x] = fw2[(x & 63) * 64 + (x >> 6)];
  for (int x = t; x < 8192; x += 256) { const int k = x >> 7, cu = x & 127; w3T[cu * 64 + k] = fw3[x]; }
  __syncthreads();
  const int e = blockIdx.x * 256 + t;
  if (e >= E) return;
  const int src = eidx[e];
  const int dst = eidx[E + e];
  const float4 emb0 = *(const float4*)(eemb + (size_t)e * 8);
  const float4 emb1 = *(const float4*)(eemb + (size_t)e * 8 + 4);
  const float emb[8] = {emb0.x, emb0.y, emb0.z, emb0.w, emb1.x, emb1.y, emb1.z, emb1.w};
  const float inv_sqrt8 = 0.35355339059327373f;
  float h1[64];
#pragma unroll
  for (int j = 0; j < 64; ++j) {
    const float4* p = (const float4*)(w1T + j * 8);
    const float4 wa = p[0], wb = p[1];
    float acc = emb[0] * wa.x + emb[1] * wa.y + emb[2] * wa.z + emb[3] * wa.w
              + emb[4] * wb.x + emb[5] * wb.y + emb[6] * wb.z + emb[7] * wb.w;
    h1[j] = silu(acc * inv_sqrt8);
  }
  float h2[64];
#pragma unroll
  for (int j = 0; j < 64; ++j) {
    const float4* p = (const float4*)(w2T + j * 64);
    float acc = 0.f;
#pragma unroll
    for (int kk = 0; kk < 16; ++kk) {
      const float4 w = p[kk];
      acc += h1[kk * 4 + 0] * w.x + h1[kk * 4 + 1] * w.y
           + h1[kk * 4 + 2] * w.z + h1[kk * 4 + 3] * w.w;
    }
    h2[j] = silu(acc * 0.125f);
  }
  const float4 ea = *(const float4*)(eattr + (size_t)e * 4);
  const float e0 = ea.x, e1x = ea.y, e1y = ea.z, e1z = ea.w;
  const float inv_sqrt3 = 0.5773502691896258f;
  const float* yrow = y + (size_t)src * 128;
  float* mrow = m + (size_t)dst * 256;
  for (int u4 = 0; u4 < 8; ++u4) {
    const int u0 = u4 * 4;
    const float4 G0 = *(const float4*)(yrow + u0);
    const float4 GA = *(const float4*)(yrow + 32 + u0 * 3);
    const float4 GB = *(const float4*)(yrow + 32 + u0 * 3 + 4);
    const float4 GC = *(const float4*)(yrow + 32 + u0 * 3 + 8);
    const float g0[4]    = {G0.x, G0.y, G0.z, G0.w};
    const float g1[4][3] = {{GA.x, GA.y, GA.z}, {GA.w, GB.x, GB.y},
                            {GB.z, GB.w, GC.x}, {GC.y, GC.z, GC.w}};
    float a[4][4];
#pragma unroll
    for (int q = 0; q < 4; ++q)
#pragma unroll
      for (int c = 0; c < 4; ++c) a[q][c] = 0.f;
#pragma unroll
    for (int kk = 0; kk < 16; ++kk) {
#pragma unroll
      for (int q = 0; q < 4; ++q) {
#pragma unroll
        for (int c = 0; c < 4; ++c) {
          const float4 w = *(const float4*)(w3T + (c * 32 + u0 + q) * 64 + kk * 4);
          a[q][c] += h2[kk * 4 + 0] * w.x + h2[kk * 4 + 1] * w.y
                   + h2[kk * 4 + 2] * w.z + h2[kk * 4 + 3] * w.w;
        }
      }
    }
#pragma unroll
    for (int q = 0; q < 4; ++q) {
      const int u = u0 + q;
      const float w00 = a[q][0] * 0.125f, w01 = a[q][1] * 0.125f;
      const float w10 = a[q][2] * 0.125f, w11 = a[q][3] * 0.125f;
      const float os0 = w00 * g0[q] * e0;
      const float dotg = g1[q][0] * e1x + g1[q][1] * e1y + g1[q][2] * e1z;
      const float os1 = w11 * dotg * inv_sqrt3;
      const float t01 = w01 * g0[q];
      const float wg  = w10 * e0;
      atomicAdd(mrow + u, os0);
      atomicAdd(mrow + 32 + u, os1);
      atomicAdd(mrow + 64 + u * 3 + 0, t01 * e1x);
      atomicAdd(mrow + 64 + u * 3 + 1, t01 * e1y);
      atomicAdd(mrow + 64 + u * 3 + 2, t01 * e1z);
      atomicAdd(mrow + 160 + u * 3 + 0, wg * g1[q][0]);
      atomicAdd(mrow + 160 + u * 3 + 1, wg * g1[q][1]);
      atomicAdd(mrow + 160 + u * 3 + 2, wg * g1[q][2]);
    }
  }
}

__global__ __launch_bounds__(192) void node_out_kernel(
    const float* __restrict__ nf, const float* __restrict__ mg,
    const float* __restrict__ sc, const float* __restrict__ w0,
    const float* __restrict__ w1, const int* __restrict__ avgp,
    float* __restrict__ out)
{
  __shared__ float sm[256];
  __shared__ float so0[64];
  __shared__ float so1[96];
  const int n = blockIdx.x, t = threadIdx.x;
  const float inv_avg = rsqrtf((float)(*avgp));
  for (int k = t; k < 256; k += 192) sm[k] = mg[n * 256 + k] * inv_avg;
  __syncthreads();
  if (t < 64) {
    float acc = 0.f;
    for (int u = 0; u < 64; ++u) acc += sm[u] * w0[u * 64 + t];
    so0[t] = acc * 0.125f + sc[n * 160 + t];
  } else if (t < 160) {
    const int q = t - 64, w = q / 3, i = q - w * 3;
    float acc = 0.f;
    for (int u = 0; u < 64; ++u) acc += sm[64 + u * 3 + i] * w1[u * 32 + w];
    so1[w * 3 + i] = acc * 0.125f + sc[n * 160 + 64 + w * 3 + i];
  }
  __syncthreads();
  if (t < 32) {
    out[n * 128 + t] = nf[n * 128 + t] + silu(so0[t]);
  } else if (t < 128) {
    const int q = t - 32, w = q / 3, i = q - w * 3;
    out[n * 128 + t] = nf[n * 128 + t] + silu(so0[32 + w]) * so1[w * 3 + i];
  }
}

extern "C" void kernel_launch(void* const* d_in, const int* in_sizes, int n_in,
                              void* d_out, int out_size, void* d_ws, size_t ws_size,
                              hipStream_t stream)
{
  const float* nf    = (const float*)d_in[0];
  const float* na    = (const float*)d_in[1];
  const float* eattr = (const float*)d_in[2];
  const float* eemb  = (const float*)d_in[3];
  const float* l1w0  = (const float*)d_in[4];
  const float* l1w1  = (const float*)d_in[5];
  const float* fw1   = (const float*)d_in[6];
  const float* fw2   = (const float*)d_in[7];
  const float* fw3   = (const float*)d_in[8];
  const float* l2w0  = (const float*)d_in[9];
  const float* l2w1  = (const float*)d_in[10];
  const float* scw0  = (const float*)d_in[11];
  const float* scw1  = (const float*)d_in[12];
  const int*   eidx  = (const int*)d_in[13];
  const int*   avgp  = (const int*)d_in[14];

  const int N = in_sizes[0] / 128;
  const int E = in_sizes[2] / 4;

  const size_t need = ((size_t)N * (128 + 160 + 3) + (size_t)E * 129 + 1) * 4;

  if (ws_size >= need) {
    float* y       = (float*)d_ws;                    // N*128
    float* sc      = y + (size_t)N * 128;             // N*160
    float* wbuf    = sc + (size_t)N * 160;            // E*128
    int*   counts  = (int*)(wbuf + (size_t)E * 128);  // N
    int*   offsets = counts + N;                      // N+1
    int*   cursor  = offsets + N + 1;                 // N
    int*   elist   = cursor + N;                      // E

    hipMemsetAsync(counts, 0, (size_t)N * sizeof(int), stream);
    node_pre_kernel<<<N, 320, 0, stream>>>(nf, na, l1w0, l1w1, scw0, scw1, y, sc);
    edge_mlp_kernel<<<(E + 255) / 256, 256, 0, stream>>>(eemb, fw1, fw2, fw3, wbuf, E);
    hist_kernel<<<(E + 255) / 256, 256, 0, stream>>>(eidx, counts, E);
    scan_kernel<<<1, 1024, 0, stream>>>(counts, offsets, cursor, N);
    scatter_kernel<<<(E + 255) / 256, 256, 0, stream>>>(eidx, cursor, elist, E);
    gather_out_kernel<<<N, 256, 0, stream>>>(nf, wbuf, y, sc, l2w0, l2w1,
                                             offsets, elist, eidx, eattr, avgp,
                                             (float*)d_out, E);
  } else {
    float* m  = (float*)d_ws;
    float* y  = m + (size_t)N * 256;
    float* sc = y + (size_t)N * 128;
    hipMemsetAsync(m, 0, (size_t)N * 256 * sizeof(float), stream);
    node_pre_kernel<<<N, 320, 0, stream>>>(nf, na, l1w0, l1w1, scw0, scw1, y, sc);
    edge_kernel_atomic<<<(E + 255) / 256, 256, 0, stream>>>(eattr, eemb, fw1, fw2, fw3, eidx, y, m, E);
    node_out_kernel<<<N, 192, 0, stream>>>(nf, m, sc, l2w0, l2w1, avgp, (float*)d_out);
  }
}

// Round 3
// 558.297 us; speedup vs baseline: 7.6332x; 1.4589x over previous
//
#include <hip/hip_runtime.h>
#include <math.h>

__device__ __forceinline__ float silu(float x) { return x / (1.0f + __expf(-x)); }

// ---------------- Kernel 1: per-node precompute ----------------
__global__ __launch_bounds__(320) void node_pre_kernel(
    const float* __restrict__ nf, const float* __restrict__ na,
    const float* __restrict__ w0, const float* __restrict__ w1,
    const float* __restrict__ scw0, const float* __restrict__ scw1,
    float* __restrict__ y, float* __restrict__ sc)
{
  __shared__ float snf[128];
  __shared__ float sna[4];
  const int n = blockIdx.x;
  const int t = threadIdx.x;
  if (t < 128) snf[t] = nf[n * 128 + t];
  if (t >= 128 && t < 132) sna[t - 128] = na[n * 4 + (t - 128)];
  __syncthreads();
  const float inv_sqrt32 = 0.17677669529663687f;
  const float sc_norm    = 0.08838834764831843f;  // 1/sqrt(32*4)
  if (t < 32) {
    const int w = t;
    float acc = 0.f;
    for (int u = 0; u < 32; ++u) acc += snf[u] * w0[u * 32 + w];
    y[n * 128 + w] = acc * inv_sqrt32;
  } else if (t < 128) {
    const int q = t - 32, w = q / 3, i = q - w * 3;
    float acc = 0.f;
    for (int u = 0; u < 32; ++u) acc += snf[32 + u * 3 + i] * w1[u * 32 + w];
    y[n * 128 + 32 + w * 3 + i] = acc * inv_sqrt32;
  } else if (t < 192) {
    const int w = t - 128;
    float acc = 0.f;
    for (int k = 0; k < 128; ++k) acc += snf[k >> 2] * sna[k & 3] * scw0[k * 64 + w];
    sc[n * 160 + w] = acc * sc_norm;
  } else if (t < 288) {
    const int q = t - 192, w = q / 3, i = q - w * 3;
    float acc = 0.f;
    for (int k = 0; k < 128; ++k) acc += snf[32 + (k >> 2) * 3 + i] * sna[k & 3] * scw1[k * 32 + w];
    sc[n * 160 + 64 + w * 3 + i] = acc * sc_norm;
  }
}

// ---------------- Kernel 2a: layers 1+2 -> h2 into wbuf[:,0:64] ------------
__global__ __launch_bounds__(256, 4) void edge_h2_kernel(
    const float* __restrict__ eemb, const float* __restrict__ fw1,
    const float* __restrict__ fw2, float* __restrict__ wbuf, int E)
{
  __shared__ __align__(16) float w1L[512];    // [k<64][r<8] (transposed)
  __shared__ __align__(16) float w2L[4096];   // [k<64][j<64] (as-is)
  const int t = threadIdx.x;
  for (int x = t; x < 512; x += 256)  w1L[x] = fw1[(x & 7) * 64 + (x >> 3)];
  for (int x = t; x < 4096; x += 256) w2L[x] = fw2[x];
  __syncthreads();

  const int e = blockIdx.x * 256 + t;
  if (e >= E) return;
  const float4 emb0 = *(const float4*)(eemb + (size_t)e * 8);
  const float4 emb1 = *(const float4*)(eemb + (size_t)e * 8 + 4);
  const float inv_sqrt8 = 0.35355339059327373f;

  float acc[64];
#pragma unroll
  for (int j = 0; j < 64; ++j) acc[j] = 0.f;

  for (int k = 0; k < 64; ++k) {
    const float4* wp = (const float4*)(w1L + k * 8);
    const float4 wa = wp[0], wb = wp[1];
    float a = emb0.x * wa.x + emb0.y * wa.y + emb0.z * wa.z + emb0.w * wa.w
            + emb1.x * wb.x + emb1.y * wb.y + emb1.z * wb.z + emb1.w * wb.w;
    const float h1k = silu(a * inv_sqrt8);
    const float4* row = (const float4*)(w2L + k * 64);
#pragma unroll
    for (int jj = 0; jj < 16; ++jj) {
      const float4 w = row[jj];
      acc[jj * 4 + 0] += h1k * w.x;
      acc[jj * 4 + 1] += h1k * w.y;
      acc[jj * 4 + 2] += h1k * w.z;
      acc[jj * 4 + 3] += h1k * w.w;
    }
  }
  float* out = wbuf + (size_t)e * 128;
#pragma unroll
  for (int j = 0; j < 64; j += 4) {
    float4 v;
    v.x = silu(acc[j + 0] * 0.125f);
    v.y = silu(acc[j + 1] * 0.125f);
    v.z = silu(acc[j + 2] * 0.125f);
    v.w = silu(acc[j + 3] * 0.125f);
    *(float4*)(out + j) = v;
  }
}

// ---------------- Kernel 2b: layer 3 -> w overwrites own wbuf row ----------
__global__ __launch_bounds__(256, 3) void edge_w3_kernel(
    const float* __restrict__ fw3, float* __restrict__ wbuf, int E)
{
  __shared__ __align__(16) float w3L[8192];   // [k<64][c<128] (as-is)
  const int t = threadIdx.x;
  for (int x = t; x < 8192; x += 256) w3L[x] = fw3[x];
  __syncthreads();

  const int e = blockIdx.x * 256 + t;
  if (e >= E) return;
  float* row = wbuf + (size_t)e * 128;

  float h2[64];
#pragma unroll
  for (int j = 0; j < 64; j += 4) {
    const float4 v = *(const float4*)(row + j);
    h2[j] = v.x; h2[j + 1] = v.y; h2[j + 2] = v.z; h2[j + 3] = v.w;
  }

  for (int c0 = 0; c0 < 128; c0 += 32) {
    float aw[32];
#pragma unroll
    for (int c = 0; c < 32; ++c) aw[c] = 0.f;
#pragma unroll
    for (int k = 0; k < 64; ++k) {          // fully unrolled: h2[k] static
      const float4* wr = (const float4*)(w3L + k * 128 + c0);
#pragma unroll
      for (int cc = 0; cc < 8; ++cc) {
        const float4 w = wr[cc];
        aw[cc * 4 + 0] += h2[k] * w.x;
        aw[cc * 4 + 1] += h2[k] * w.y;
        aw[cc * 4 + 2] += h2[k] * w.z;
        aw[cc * 4 + 3] += h2[k] * w.w;
      }
    }
#pragma unroll
    for (int c = 0; c < 32; c += 4) {
      float4 v;
      v.x = aw[c] * 0.125f; v.y = aw[c + 1] * 0.125f;
      v.z = aw[c + 2] * 0.125f; v.w = aw[c + 3] * 0.125f;
      *(float4*)(row + c0 + c) = v;
    }
  }
}

// ---------------- CSR build ----------------
__global__ __launch_bounds__(256) void hist_kernel(const int* __restrict__ eidx,
                                                   int* __restrict__ counts, int E)
{
  const int e = blockIdx.x * 256 + threadIdx.x;
  if (e < E) atomicAdd(&counts[eidx[E + e]], 1);
}

__global__ __launch_bounds__(1024) void scan_kernel(const int* __restrict__ counts,
                                                    int* __restrict__ offsets,
                                                    int* __restrict__ cursor, int N)
{
  __shared__ int part[1024];
  const int t = threadIdx.x;
  const int per = (N + 1023) / 1024;
  const int base = t * per;
  int s = 0;
  for (int k = 0; k < per; ++k) { int idx = base + k; if (idx < N) s += counts[idx]; }
  part[t] = s;
  __syncthreads();
  for (int off = 1; off < 1024; off <<= 1) {
    int v = part[t];
    if (t >= off) v += part[t - off];
    __syncthreads();
    part[t] = v;
    __syncthreads();
  }
  int run = (t == 0) ? 0 : part[t - 1];
  for (int k = 0; k < per; ++k) {
    int idx = base + k;
    if (idx < N) { offsets[idx] = run; cursor[idx] = run; run += counts[idx]; }
  }
  if (t == 1023) offsets[N] = run;
}

__global__ __launch_bounds__(256) void scatter_kernel(const int* __restrict__ eidx,
                                                      int* __restrict__ cursor,
                                                      int* __restrict__ elist, int E)
{
  const int e = blockIdx.x * 256 + threadIdx.x;
  if (e >= E) return;
  const int dst = eidx[E + e];
  const int slot = atomicAdd(&cursor[dst], 1);
  elist[slot] = e;
}

// ---------------- Kernel 3: gather + tensor product + lin2 + gate + residual --
__global__ __launch_bounds__(256) void gather_out_kernel(
    const float* __restrict__ nf, const float* __restrict__ wbuf,
    const float* __restrict__ y, const float* __restrict__ sc,
    const float* __restrict__ l2w0, const float* __restrict__ l2w1,
    const int* __restrict__ offsets, const int* __restrict__ elist,
    const int* __restrict__ eidx, const float* __restrict__ eattr,
    const int* __restrict__ avgp, float* __restrict__ out, int E)
{
  __shared__ float sm[256];
  __shared__ float so0[64];
  __shared__ float so1[96];
  const int n = blockIdx.x, t = threadIdx.x;

  int wi, yi0, yi1, yi2, selA;  // selA: 0=e0,1=e1x,2=e1y,3=e1z
  bool is1 = false;
  if (t < 32) {            // o_s0[u]
    wi = t; yi0 = yi1 = yi2 = t; selA = 0;
  } else if (t < 64) {     // o_s1[u]
    const int u = t - 32;
    wi = 96 + u; yi0 = 32 + 3 * u; yi1 = yi0 + 1; yi2 = yi0 + 2; selA = 1; is1 = true;
  } else if (t < 160) {    // o_v0[u][i]
    const int q = t - 64, u = q / 3, i = q - u * 3;
    wi = 32 + u; yi0 = yi1 = yi2 = u; selA = 1 + i;
  } else {                 // o_v1[u][i]
    const int q = t - 160, u = q / 3, i = q - u * 3;
    wi = 64 + u; yi0 = yi1 = yi2 = 32 + 3 * u + i; selA = 0;
  }

  const int beg = offsets[n], end = offsets[n + 1];
  float accv = 0.f;
  int eid = (beg < end) ? elist[beg] : 0;
  for (int j = beg; j < end; ++j) {
    const int eidn = (j + 1 < end) ? elist[j + 1] : 0;
    const int src = eidx[eid];
    const float4 ea = *(const float4*)(eattr + (size_t)eid * 4);
    const float* wr = wbuf + (size_t)eid * 128;
    const float* yr = y + (size_t)src * 128;
    const float A = (selA == 0) ? ea.x : (selA == 1) ? ea.y : (selA == 2) ? ea.z : ea.w;
    const float B = is1 ? ea.z : 0.f;
    const float C = is1 ? ea.w : 0.f;
    accv += wr[wi] * (A * yr[yi0] + B * yr[yi1] + C * yr[yi2]);
    eid = eidn;
  }
  const float inv_sqrt3 = 0.5773502691896258f;
  if (is1) accv *= inv_sqrt3;
  sm[t] = accv * rsqrtf((float)(*avgp));
  __syncthreads();

  if (t < 64) {
    float acc = 0.f;
    for (int u = 0; u < 64; ++u) acc += sm[u] * l2w0[u * 64 + t];
    so0[t] = acc * 0.125f + sc[n * 160 + t];
  } else if (t < 160) {
    const int q = t - 64, w = q / 3, i = q - w * 3;
    float acc = 0.f;
    for (int u = 0; u < 64; ++u) acc += sm[64 + u * 3 + i] * l2w1[u * 32 + w];
    so1[w * 3 + i] = acc * 0.125f + sc[n * 160 + 64 + w * 3 + i];
  }
  __syncthreads();
  if (t < 32) {
    out[n * 128 + t] = nf[n * 128 + t] + silu(so0[t]);
  } else if (t < 128) {
    const int q = t - 32, w = q / 3, i = q - w * 3;
    out[n * 128 + t] = nf[n * 128 + t] + silu(so0[32 + w]) * so1[w * 3 + i];
  }
}

extern "C" void kernel_launch(void* const* d_in, const int* in_sizes, int n_in,
                              void* d_out, int out_size, void* d_ws, size_t ws_size,
                              hipStream_t stream)
{
  const float* nf    = (const float*)d_in[0];
  const float* na    = (const float*)d_in[1];
  const float* eattr = (const float*)d_in[2];
  const float* eemb  = (const float*)d_in[3];
  const float* l1w0  = (const float*)d_in[4];
  const float* l1w1  = (const float*)d_in[5];
  const float* fw1   = (const float*)d_in[6];
  const float* fw2   = (const float*)d_in[7];
  const float* fw3   = (const float*)d_in[8];
  const float* l2w0  = (const float*)d_in[9];
  const float* l2w1  = (const float*)d_in[10];
  const float* scw0  = (const float*)d_in[11];
  const float* scw1  = (const float*)d_in[12];
  const int*   eidx  = (const int*)d_in[13];
  const int*   avgp  = (const int*)d_in[14];

  const int N = in_sizes[0] / 128;
  const int E = in_sizes[2] / 4;

  float* y       = (float*)d_ws;                    // N*128
  float* sc      = y + (size_t)N * 128;             // N*160
  float* wbuf    = sc + (size_t)N * 160;            // E*128
  int*   counts  = (int*)(wbuf + (size_t)E * 128);  // N
  int*   offsets = counts + N;                      // N+1
  int*   cursor  = offsets + N + 1;                 // N
  int*   elist   = cursor + N;                      // E

  hipMemsetAsync(counts, 0, (size_t)N * sizeof(int), stream);
  node_pre_kernel<<<N, 320, 0, stream>>>(nf, na, l1w0, l1w1, scw0, scw1, y, sc);
  edge_h2_kernel<<<(E + 255) / 256, 256, 0, stream>>>(eemb, fw1, fw2, wbuf, E);
  edge_w3_kernel<<<(E + 255) / 256, 256, 0, stream>>>(fw3, wbuf, E);
  hist_kernel<<<(E + 255) / 256, 256, 0, stream>>>(eidx, counts, E);
  scan_kernel<<<1, 1024, 0, stream>>>(counts, offsets, cursor, N);
  scatter_kernel<<<(E + 255) / 256, 256, 0, stream>>>(eidx, cursor, elist, E);
  gather_out_kernel<<<N, 256, 0, stream>>>(nf, wbuf, y, sc, l2w0, l2w1,
                                           offsets, elist, eidx, eattr, avgp,
                                           (float*)d_out, E);
}